// Round 1
// baseline (1006.877 us; speedup 1.0000x reference)
//
#include <hip/hip_runtime.h>
#include <hip/hip_bf16.h>
#include <math.h>

#define NQ 8192      // queries (rows of `outputs`)
#define NC 32000     // classes
#define NT 128       // targets (rows of the transposed cost)

// ---------------------------------------------------------------------------
// Kernel A: per-row softmax stats + transposed cost build.
// One block per query row. C_T[t][q] = 1 - (float)(exp(x[q,tgt[t]]-M_q)/S_q)
// ---------------------------------------------------------------------------
__global__ __launch_bounds__(256) void build_cost(
    const float* __restrict__ outp, const int* __restrict__ tgt,
    float* __restrict__ C)
{
  const int row = blockIdx.x;
  const int tid = threadIdx.x;
  const float* x = outp + (size_t)row * NC;

  // online per-thread max + f64 sum of f32 exp terms (float4 loads)
  float m = -INFINITY;
  double s = 0.0;
  const float4* x4 = (const float4*)x;
  for (int k = tid; k < NC / 4; k += 256) {
    float4 v = x4[k];
    float mv = fmaxf(fmaxf(v.x, v.y), fmaxf(v.z, v.w));
    if (mv > m) { s *= exp((double)(m - mv)); m = mv; }  // exp(-inf)=0 first time
    s += (double)__expf(v.x - m) + (double)__expf(v.y - m)
       + (double)__expf(v.z - m) + (double)__expf(v.w - m);
  }

  __shared__ float  lsm[4];
  __shared__ double lss[4];
  __shared__ float  bM;
  __shared__ double bS;

  // block max (exact; order-independent)
  float wm = m;
  #pragma unroll
  for (int off = 32; off; off >>= 1) wm = fmaxf(wm, __shfl_xor(wm, off));
  const int wid = tid >> 6;
  if ((tid & 63) == 0) lsm[wid] = wm;
  __syncthreads();
  if (tid == 0) bM = fmaxf(fmaxf(lsm[0], lsm[1]), fmaxf(lsm[2], lsm[3]));
  __syncthreads();
  const float M = bM;

  // block sum of rescaled partial sums (f64)
  double s2 = s * exp((double)m - (double)M);
  #pragma unroll
  for (int off = 32; off; off >>= 1) s2 += __shfl_xor(s2, off);
  if ((tid & 63) == 0) lss[wid] = s2;
  __syncthreads();
  if (tid == 0) bS = lss[0] + lss[1] + lss[2] + lss[3];
  __syncthreads();
  const double S = bS;

  // gather the 128 target columns; write transposed cost
  if (tid < NT) {
    const int c = tgt[tid];
    const double p = exp((double)x[c] - (double)M) / S;
    C[(size_t)tid * NQ + row] = 1.0f - (float)p;
  }
}

// ---------------------------------------------------------------------------
// Kernel B: exact Jonker-Volgenant LSAP on the 128 x 8192 cost (f64 math),
// replicating scipy/numpy semantics (operation order + argmin tie-breaks).
// Single block, 1024 threads; each thread owns 8 columns (j = k*1024 + tid).
// ---------------------------------------------------------------------------
__global__ __launch_bounds__(1024) void lsap_solve(
    const float* __restrict__ C, int* __restrict__ outi)
{
  const int tid = threadIdx.x;

  __shared__ short          row4col[NQ];    // 16 KB
  __shared__ unsigned short path[NQ];       // 16 KB (stores row idx < 128)
  __shared__ short          col4row[NT];
  __shared__ double         u[NT];
  __shared__ int            jlist[160];     // scanned columns, in scan order
  __shared__ double         mvlist[160];    // shortest value frozen at scan
  __shared__ short          ilist[160];     // row entered via that column (-1 = sink)
  __shared__ double         wredv[16];
  __shared__ int            wredj[16];
  __shared__ double         bc_minval;
  __shared__ int            bc_i, bc_j, bc_sink, listcnt;

  double sh[8];       // shortest[j] for owned columns
  double vv[8];       // v[j] for owned columns
  unsigned scmask;    // SC bits for owned columns

  for (int j = tid; j < NQ; j += 1024) row4col[j] = -1;
  if (tid < NT) { col4row[tid] = -1; u[tid] = 0.0; }
  #pragma unroll
  for (int k = 0; k < 8; ++k) vv[k] = 0.0;
  __syncthreads();

  for (int cur = 0; cur < NT; ++cur) {
    scmask = 0u;
    #pragma unroll
    for (int k = 0; k < 8; ++k) sh[k] = INFINITY;
    if (tid == 0) { bc_i = cur; bc_minval = 0.0; bc_sink = -1; listcnt = 0; }
    __syncthreads();

    // shortest augmenting path (Dijkstra-style)
    while (true) {
      const int    i      = bc_i;
      const double minval = bc_minval;
      const double ui     = u[i];
      const float* crow   = C + (size_t)i * NQ;

      double best  = INFINITY;
      int    bestj = 0x7fffffff;
      #pragma unroll
      for (int k = 0; k < 8; ++k) {
        if (!((scmask >> k) & 1u)) {
          const int j = (k << 10) + tid;
          // numpy order: ((min_val + cost) - u[i]) - v[j]
          const double r = ((minval + (double)crow[j]) - ui) - vv[k];
          if (r < sh[k]) { sh[k] = r; path[j] = (unsigned short)i; }
          if (sh[k] < best) { best = sh[k]; bestj = j; }  // k asc => j asc ties keep smallest
        }
      }
      // wave butterfly (val, j) lexicographic min
      #pragma unroll
      for (int off = 32; off; off >>= 1) {
        const double ov = __shfl_xor(best, off);
        const int    oj = __shfl_xor(bestj, off);
        if (ov < best || (ov == best && oj < bestj)) { best = ov; bestj = oj; }
      }
      const int wid = tid >> 6;
      if ((tid & 63) == 0) { wredv[wid] = best; wredj[wid] = bestj; }
      __syncthreads();
      if (tid == 0) {
        double mb = wredv[0]; int mj = wredj[0];
        for (int w = 1; w < 16; ++w) {
          const double ov = wredv[w]; const int oj = wredj[w];
          if (ov < mb || (ov == mb && oj < mj)) { mb = ov; mj = oj; }
        }
        bc_minval = mb; bc_j = mj;
        const int cnt = listcnt;
        jlist[cnt]  = mj;
        mvlist[cnt] = mb;
        const short ri = row4col[mj];
        ilist[cnt]  = ri;
        listcnt     = cnt + 1;
        if (ri < 0) bc_sink = mj; else bc_i = ri;
      }
      __syncthreads();
      const int jstar = bc_j;
      if ((jstar & 1023) == tid) scmask |= 1u << (jstar >> 10);
      if (bc_sink >= 0) break;
    }

    // dual updates (matching numpy: u[cur]+=mv; u[oi]+=mv-shortest[col4row[oi]];
    // v[ci]-=mv-shortest[ci]; scanned columns' shortest frozen at scan time)
    const double minval = bc_minval;
    const int    cnt    = listcnt;
    if (tid == 0) u[cur] += minval;
    if (tid < cnt) {
      const int ri = ilist[tid];
      if (ri >= 0) u[ri] += minval - mvlist[tid];
    }
    for (int e = 0; e < cnt; ++e) {
      const int j = jlist[e];
      if ((j & 1023) == tid) vv[j >> 10] -= (minval - mvlist[e]);
    }
    __syncthreads();

    // augment along the alternating path
    if (tid == 0) {
      int j = bc_sink;
      while (true) {
        const int i2 = path[j];
        row4col[j] = (short)i2;
        const int jn = col4row[i2];
        col4row[i2] = (short)j;
        j = jn;
        if (i2 == cur) break;
      }
    }
    __syncthreads();
  }

  // transposed-case output: rows = col4row (query idx), cols = arange(NT),
  // sorted ascending by query idx. Values distinct -> rank sort.
  if (tid < NT) {
    const int q = col4row[tid];
    int rank = 0;
    for (int k = 0; k < NT; ++k) rank += (col4row[k] < q);
    outi[rank]      = q;
    outi[NT + rank] = tid;
  }
}

extern "C" void kernel_launch(void* const* d_in, const int* in_sizes, int n_in,
                              void* d_out, int out_size, void* d_ws, size_t ws_size,
                              hipStream_t stream) {
  (void)in_sizes; (void)n_in; (void)out_size; (void)ws_size;
  const float* outputs = (const float*)d_in[0];
  const int*   targets = (const int*)d_in[1];
  float* C   = (float*)d_ws;          // 128 x 8192 f32 = 4 MB
  int*   out = (int*)d_out;           // 256 int32: row_ind || col_ind

  build_cost<<<NQ, 256, 0, stream>>>(outputs, targets, C);
  lsap_solve<<<1, 1024, 0, stream>>>(C, out);
}

// Round 2
// 623.903 us; speedup vs baseline: 1.6138x; 1.6138x over previous
//
#include <hip/hip_runtime.h>
#include <hip/hip_bf16.h>
#include <math.h>

#define NQ 8192      // queries (columns of the transposed cost)
#define NC 32000     // classes
#define NT 128       // targets (rows of the transposed cost)

// ---------------------------------------------------------------------------
// Kernel A: per-row softmax stats + transposed cost build.
// One block per query row. C[t][q] = 1 - (float)(exp(x[q,tgt[t]]-M_q)/S_q)
// ---------------------------------------------------------------------------
__global__ __launch_bounds__(256) void build_cost(
    const float* __restrict__ outp, const int* __restrict__ tgt,
    float* __restrict__ C)
{
  const int row = blockIdx.x;
  const int tid = threadIdx.x;
  const float* x = outp + (size_t)row * NC;

  float m = -INFINITY;
  double s = 0.0;
  const float4* x4 = (const float4*)x;
  for (int k = tid; k < NC / 4; k += 256) {
    float4 v = x4[k];
    float mv = fmaxf(fmaxf(v.x, v.y), fmaxf(v.z, v.w));
    if (mv > m) { s *= exp((double)(m - mv)); m = mv; }
    s += (double)__expf(v.x - m) + (double)__expf(v.y - m)
       + (double)__expf(v.z - m) + (double)__expf(v.w - m);
  }

  __shared__ float  lsm[4];
  __shared__ double lss[4];
  __shared__ float  bM;
  __shared__ double bS;

  float wm = m;
  #pragma unroll
  for (int off = 32; off; off >>= 1) wm = fmaxf(wm, __shfl_xor(wm, off));
  const int wid = tid >> 6;
  if ((tid & 63) == 0) lsm[wid] = wm;
  __syncthreads();
  if (tid == 0) bM = fmaxf(fmaxf(lsm[0], lsm[1]), fmaxf(lsm[2], lsm[3]));
  __syncthreads();
  const float M = bM;

  double s2 = s * exp((double)m - (double)M);
  #pragma unroll
  for (int off = 32; off; off >>= 1) s2 += __shfl_xor(s2, off);
  if ((tid & 63) == 0) lss[wid] = s2;
  __syncthreads();
  if (tid == 0) bS = lss[0] + lss[1] + lss[2] + lss[3];
  __syncthreads();
  const double S = bS;

  if (tid < NT) {
    const int c = tgt[tid];
    const double p = exp((double)x[c] - (double)M) / S;
    C[(size_t)tid * NQ + row] = 1.0f - (float)p;
  }
}

// ---------------------------------------------------------------------------
// Kernel B: per-target-row sort by (cost_bits, col). Keys packed u64:
// (f32_bits(c) << 32) | j. c >= 0 so bit order == value order.
// LDS bitonic sort of 8192 keys per block; 128 blocks run in parallel.
// ---------------------------------------------------------------------------
__global__ __launch_bounds__(256) void sort_rows(
    const float* __restrict__ C, unsigned long long* __restrict__ S)
{
  __shared__ unsigned long long key[NQ];   // 64 KB
  const int t = blockIdx.x, tid = threadIdx.x;
  const float* crow = C + (size_t)t * NQ;
  for (int i = tid; i < NQ; i += 256)
    key[i] = ((unsigned long long)__float_as_uint(crow[i]) << 32) | (unsigned)i;
  for (int k = 2; k <= NQ; k <<= 1)
    for (int jj = k >> 1; jj > 0; jj >>= 1) {
      __syncthreads();
      for (int w = tid; w < NQ / 2; w += 256) {
        const int i1 = ((w & ~(jj - 1)) << 1) | (w & (jj - 1));
        const int i2 = i1 | jj;
        const bool up = ((i1 & k) == 0);
        const unsigned long long a = key[i1], b = key[i2];
        if ((a > b) == up) { key[i1] = b; key[i2] = a; }
      }
    }
  __syncthreads();
  unsigned long long* srow = S + (size_t)t * NQ;
  for (int i = tid; i < NQ; i += 256) srow[i] = key[i];
}

// ---------------------------------------------------------------------------
// Kernel C: exact JV LSAP, single wave (64 lanes), barrier-free.
// A-set (assigned columns, <=128) lives in registers: slot s owned by lane
// s&63, bank A (s<64) or B (s>=64). U-side candidates come from the
// pre-sorted rows: first unassigned entry == exact (value, smallest-j) argmin
// because v[j]==0 on never-assigned columns and the f64 transform
// ((minval + c) - u_i) - 0.0 is strictly monotone over distinct f32 c.
// ---------------------------------------------------------------------------
__global__ __launch_bounds__(64) void lsap_solve(
    const float* __restrict__ C, const unsigned long long* __restrict__ S,
    int* __restrict__ outi)
{
  const int lane = threadIdx.x;

  __shared__ double u[NT];
  __shared__ short  col4row[NT];
  __shared__ unsigned short cursor[NT];
  __shared__ unsigned long long abm[NQ / 64];   // assigned bitmap
  __shared__ unsigned short slot4col[NQ];       // 16 KB

  // per-slot register state: slot = lane (bank A) and 64+lane (bank B)
  int    acolA = -1, acolB = -1;     // column j of the slot
  int    arowA = -1, arowB = -1;     // row4col[j]
  int    apathA = -1, apathB = -1;   // path[j]
  double avA = 0.0, avB = 0.0;       // v[j]
  double ashA = 0.0, ashB = 0.0;     // shortest[j]
  double afzA = 0.0, afzB = 0.0;     // shortest frozen at selection
  bool   ascA = false, ascB = false; // SC[j]
  int    nA = 0;

  u[lane] = 0.0;        u[64 + lane] = 0.0;
  col4row[lane] = -1;   col4row[64 + lane] = -1;
  cursor[lane] = 0;     cursor[64 + lane] = 0;
  abm[lane] = 0ull;     abm[64 + lane] = 0ull;

  for (int cur = 0; cur < NT; ++cur) {
    ashA = INFINITY; ashB = INFINITY; ascA = false; ascB = false;
    double ub_r = INFINITY; int ub_j = 0x7fffffff, ub_i = -1;  // running U-best
    int icur = cur; double minval = 0.0;
    int sink = -1, sinkpath = -1;

    while (sink < 0) {
      const double u_i = u[icur];
      const float* crow = C + (size_t)icur * NQ;
      const bool actA = (lane < nA) && !ascA;
      const bool actB = (64 + lane < nA) && !ascB;
      float cA = 0.f, cB = 0.f;
      if (actA) cA = crow[acolA];
      if (actB) cB = crow[acolB];

      // --- U-side: first unassigned entry of the sorted row (persistent cursor)
      int pos = cursor[icur];
      unsigned long long kk = 0ull;
      for (;;) {
        const unsigned long long k = S[(size_t)icur * NQ + pos + lane];
        const int j = (int)(k & 0xffffffffu);
        const bool asg = (abm[j >> 6] >> (j & 63)) & 1ull;
        const unsigned long long bal = __ballot(!asg);
        if (bal) {
          const int f = __builtin_ctzll(bal);
          kk = __shfl(k, f);
          pos += f;
          break;
        }
        pos += 64;
      }
      if (lane == 0) cursor[icur] = (unsigned short)pos;
      {
        const int jU = (int)(kk & 0xffffffffu);
        const double cU = (double)__uint_as_float((unsigned)(kk >> 32));
        const double rU = ((minval + cU) - u_i) - 0.0;  // v[j]==0 on U
        // strict lex update -> stores FIRST achiever row (numpy path semantics)
        if (rU < ub_r || (rU == ub_r && jU < ub_j)) { ub_r = rU; ub_j = jU; ub_i = icur; }
      }

      // --- A-side: update shortest over unscanned assigned columns
      double cr = INFINITY; int cj = 0x7fffffff, cs = -1;
      if (actA) {
        const double r = ((minval + (double)cA) - u_i) - avA;
        if (r < ashA) { ashA = r; apathA = icur; }
        cr = ashA; cj = acolA; cs = lane;
      }
      if (actB) {
        const double r = ((minval + (double)cB) - u_i) - avB;
        if (r < ashB) { ashB = r; apathB = icur; }
        if (ashB < cr || (ashB == cr && acolB < cj)) { cr = ashB; cj = acolB; cs = 64 + lane; }
      }
      #pragma unroll
      for (int off = 32; off; off >>= 1) {
        const double orr = __shfl_xor(cr, off);
        const int    oj  = __shfl_xor(cj, off);
        const int    os  = __shfl_xor(cs, off);
        if (orr < cr || (orr == cr && oj < cj)) { cr = orr; cj = oj; cs = os; }
      }

      // --- decision (uniform across lanes)
      if (cr < ub_r || (cr == ub_r && cj < ub_j)) {
        minval = cr;                       // select assigned column cj (slot cs)
        if (lane == (cs & 63)) {
          if (cs < 64) { ascA = true; afzA = cr; }
          else         { ascB = true; afzB = cr; }
        }
        const int rA = __shfl(arowA, cs & 63);
        const int rB = __shfl(arowB, cs & 63);
        icur = (cs < 64) ? rA : rB;        // jump to that column's row
      } else {
        minval = ub_r;
        sink = ub_j; sinkpath = ub_i;      // unassigned column wins -> done
      }
    }

    // --- dual updates (owner-side; scanned slots only; sink's v-update is -0)
    if (lane == 0) u[cur] += minval;
    if (ascA) { u[arowA] += minval - afzA; avA -= (minval - afzA); }
    if (ascB) { u[arowB] += minval - afzB; avB -= (minval - afzB); }

    // --- augment along the alternating path (uniform serial)
    {
      int j = sink, i = sinkpath;
      if (lane == (nA & 63)) {            // append sink as new A slot
        if (nA < 64) { acolA = sink; avA = 0.0; arowA = i; }
        else         { acolB = sink; avB = 0.0; arowB = i; }
      }
      if (lane == 0) {
        slot4col[sink] = (unsigned short)nA;
        abm[sink >> 6] |= 1ull << (sink & 63);
      }
      nA++;
      for (;;) {
        const int jn = col4row[i];        // read before lane0's write (program order)
        if (lane == 0) col4row[i] = (short)j;
        if (i == cur) break;
        j = jn;
        const int s  = slot4col[j];
        const int pA = __shfl(apathA, s & 63);
        const int pB = __shfl(apathB, s & 63);
        const int ni = (s < 64) ? pA : pB;
        if (lane == (s & 63)) {           // row4col[j] = ni
          if (s < 64) arowA = ni; else arowB = ni;
        }
        i = ni;
      }
    }
  }

  // output: rows = col4row (query idx), cols = arange(NT), sorted by query idx
  for (int t = lane; t < NT; t += 64) {
    const int q = col4row[t];
    int rank = 0;
    for (int k = 0; k < NT; ++k) rank += (col4row[k] < q);
    outi[rank]      = q;
    outi[NT + rank] = t;
  }
}

extern "C" void kernel_launch(void* const* d_in, const int* in_sizes, int n_in,
                              void* d_out, int out_size, void* d_ws, size_t ws_size,
                              hipStream_t stream) {
  (void)in_sizes; (void)n_in; (void)out_size; (void)ws_size;
  const float* outputs = (const float*)d_in[0];
  const int*   targets = (const int*)d_in[1];
  float* C = (float*)d_ws;                                   // 4 MB
  unsigned long long* S =
      (unsigned long long*)((char*)d_ws + (size_t)NT * NQ * sizeof(float)); // 8 MB
  int* out = (int*)d_out;

  build_cost<<<NQ, 256, 0, stream>>>(outputs, targets, C);
  sort_rows<<<NT, 256, 0, stream>>>(C, S);
  lsap_solve<<<1, 64, 0, stream>>>(C, S, out);
}

// Round 4
// 504.334 us; speedup vs baseline: 1.9964x; 1.2371x over previous
//
#include <hip/hip_runtime.h>
#include <hip/hip_bf16.h>
#include <math.h>

#define NQ 8192      // queries (columns of the transposed cost)
#define NC 32000     // classes
#define NT 128       // targets (rows of the transposed cost)
#define SROW 256     // kept (smallest) sorted entries per row
#define SLOTC 120    // assigned-column slots cached in LDS (rest -> global)

typedef float v4f __attribute__((ext_vector_type(4)));

// ---------------------------------------------------------------------------
// Kernel A: per-row softmax stats + transposed cost build.
// C[t][q] = 1 - (float)(exp(x[q,tgt[t]]-M_q)/S_q)
// ---------------------------------------------------------------------------
__global__ __launch_bounds__(256) void build_cost(
    const float* __restrict__ outp, const int* __restrict__ tgt,
    float* __restrict__ C)
{
  const int row = blockIdx.x;
  const int tid = threadIdx.x;
  const float* x = outp + (size_t)row * NC;

  float m = -INFINITY;
  double s = 0.0;
  const v4f* x4 = (const v4f*)x;
  for (int k = tid; k < NC / 4; k += 256) {
    v4f v = __builtin_nontemporal_load(x4 + k);
    float mv = fmaxf(fmaxf(v.x, v.y), fmaxf(v.z, v.w));
    if (mv > m) { s *= exp((double)(m - mv)); m = mv; }
    s += (double)__expf(v.x - m) + (double)__expf(v.y - m)
       + (double)__expf(v.z - m) + (double)__expf(v.w - m);
  }

  __shared__ float  lsm[4];
  __shared__ double lss[4];
  __shared__ float  bM;
  __shared__ double bS;

  float wm = m;
  #pragma unroll
  for (int off = 32; off; off >>= 1) wm = fmaxf(wm, __shfl_xor(wm, off));
  const int wid = tid >> 6;
  if ((tid & 63) == 0) lsm[wid] = wm;
  __syncthreads();
  if (tid == 0) bM = fmaxf(fmaxf(lsm[0], lsm[1]), fmaxf(lsm[2], lsm[3]));
  __syncthreads();
  const float M = bM;

  double s2 = s * exp((double)m - (double)M);
  #pragma unroll
  for (int off = 32; off; off >>= 1) s2 += __shfl_xor(s2, off);
  if ((tid & 63) == 0) lss[wid] = s2;
  __syncthreads();
  if (tid == 0) bS = lss[0] + lss[1] + lss[2] + lss[3];
  __syncthreads();
  const double S = bS;

  if (tid < NT) {
    const int c = tgt[tid];
    const double p = exp((double)x[c] - (double)M) / S;
    C[(size_t)tid * NQ + row] = 1.0f - (float)p;
  }
}

// ---------------------------------------------------------------------------
// Kernel B: per-row top-256 selection, sorted ascending by (cost_bits, col).
// Keys u64: (f32_bits(c) << 32) | j  (c > 0 so bit order == value order).
// Phase 1: bitonic-sort each 256-chunk ascending (direction from LOCAL index).
// Phase 2: 5 rounds of pairwise top-256: CE A[i] vs B[255-i] (keeps the 256
// smallest in A as a bitonic sequence), then 8-pass bitonic merge of A.
// Solver touches at most entry 190 of a row (cursor skips only assigned
// columns, <=127 of them; ballot window +63), so 256 is sufficient.
// ---------------------------------------------------------------------------
__global__ __launch_bounds__(256) void select_rows(
    const float* __restrict__ C, unsigned long long* __restrict__ S)
{
  __shared__ unsigned long long key[NQ];   // 64 KB
  const int t = blockIdx.x, tid = threadIdx.x;
  const float* crow = C + (size_t)t * NQ;
  for (int i = tid; i < NQ; i += 256)
    key[i] = ((unsigned long long)__float_as_uint(crow[i]) << 32) | (unsigned)i;

  // phase 1: each 256-chunk sorted ascending
  for (int k = 2; k <= 256; k <<= 1)
    for (int jj = k >> 1; jj > 0; jj >>= 1) {
      __syncthreads();
      for (int w = tid; w < NQ / 2; w += 256) {
        const int i1 = ((w & ~(jj - 1)) << 1) | (w & (jj - 1));
        const int i2 = i1 | jj;
        const bool up = (((i1 & 255) & k) == 0);
        const unsigned long long a = key[i1], b = key[i2];
        if ((a > b) == up) { key[i1] = b; key[i2] = a; }
      }
    }

  // phase 2: pairwise top-256 merges (survivor chunks at multiples of 2*step)
  for (int step = 1; step < 32; step <<= 1) {
    const int npairs = 16 / step;
    __syncthreads();
    for (int w = tid; w < npairs * 256; w += 256) {
      const int p = w >> 8, i = w & 255;
      const int a = ((p * 2 * step) << 8) + i;
      const int b = ((p * 2 * step + step) << 8) + 255 - i;
      const unsigned long long ka = key[a], kb = key[b];
      if (ka > kb) key[a] = kb;          // keep min; upper half dead
    }
    for (int jj = 128; jj > 0; jj >>= 1) {
      __syncthreads();
      for (int w = tid; w < npairs * 128; w += 256) {
        const int p = w >> 7, q = w & 127;
        const int base = (p * 2 * step) << 8;
        const int i1 = base + (((q & ~(jj - 1)) << 1) | (q & (jj - 1)));
        const int i2 = i1 | jj;
        const unsigned long long a = key[i1], b = key[i2];
        if (a > b) { key[i1] = b; key[i2] = a; }
      }
    }
  }
  __syncthreads();
  unsigned long long* srow = S + (size_t)t * SROW;
  for (int i = tid; i < SROW; i += 256) srow[i] = key[i];
}

// ---------------------------------------------------------------------------
// Kernel C: exact JV LSAP, single wave, barrier-free. A-side costs cached in
// LDS (Clds[row][slot]); U-side candidate cached per row (cand/abm check).
// Semantics identical to the verified R2 solver (numpy f64 op order, strict-<
// updates, smallest-j tie-breaks, first-achiever path rows).
// ---------------------------------------------------------------------------
__global__ __launch_bounds__(64) void lsap_solve(
    const float* __restrict__ C, const unsigned long long* __restrict__ S,
    int* __restrict__ outi)
{
  const int lane = threadIdx.x;

  __shared__ float  Clds[NT][SLOTC];            // 61440 B
  __shared__ double u[NT];                      // 1 KB
  __shared__ unsigned long long cand[NT];       // 1 KB (0 = unset; keys never 0)
  __shared__ unsigned long long abm[NQ / 64];   // 1 KB assigned bitmap
  __shared__ short col4row[NT];
  __shared__ unsigned short cursor[NT];

  int    acolA = -1, acolB = -1;     // column of slot (bank A: slot=lane, B: 64+lane)
  int    arowA = -1, arowB = -1;     // row4col[col]
  int    apathA = -1, apathB = -1;   // path[col]
  double avA = 0.0, avB = 0.0;       // v[col]
  double ashA = 0.0, ashB = 0.0;     // shortest[col]
  double afzA = 0.0, afzB = 0.0;     // shortest frozen at selection
  bool   ascA = false, ascB = false; // SC[col]
  int    nA = 0;

  u[lane] = 0.0;        u[64 + lane] = 0.0;
  cand[lane] = 0ull;    cand[64 + lane] = 0ull;
  col4row[lane] = -1;   col4row[64 + lane] = -1;
  cursor[lane] = 0;     cursor[64 + lane] = 0;
  abm[lane] = 0ull;     abm[64 + lane] = 0ull;

  for (int cur = 0; cur < NT; ++cur) {
    ashA = INFINITY; ashB = INFINITY; ascA = false; ascB = false;
    double ub_r = INFINITY; int ub_j = 0x7fffffff, ub_i = -1;
    int icur = cur; double minval = 0.0;
    int sink = -1, sinkpath = -1;

    while (sink < 0) {
      const double u_i = u[icur];
      const bool actA = (lane < nA) && !ascA;
      const bool actB = (64 + lane < nA) && !ascB;
      float cA = 0.f, cB = 0.f;
      if (actA) cA = Clds[icur][lane];
      if (actB) cB = (64 + lane < SLOTC) ? Clds[icur][64 + lane]
                                         : C[(size_t)icur * NQ + acolB];

      // --- U-side: cached first-unassigned sorted candidate for this row
      unsigned long long kk = cand[icur];
      {
        const int jc = (int)(kk & 0xffffffffu);
        const bool valid = (kk != 0ull) && !((abm[jc >> 6] >> (jc & 63)) & 1ull);
        if (!valid) {
          int pos = cursor[icur];
          for (;;) {
            const unsigned long long k = S[(size_t)icur * SROW + pos + lane];
            const int j = (int)(k & 0xffffffffu);
            const bool asg = (abm[j >> 6] >> (j & 63)) & 1ull;
            const unsigned long long bal = __ballot(!asg);
            if (bal) {
              const int f = __builtin_ctzll(bal);
              kk = __shfl(k, f);
              pos += f;
              break;
            }
            pos += 64;
          }
          if (lane == 0) { cursor[icur] = (unsigned short)pos; cand[icur] = kk; }
        }
      }
      {
        const int    jU = (int)(kk & 0xffffffffu);
        const double cU = (double)__uint_as_float((unsigned)(kk >> 32));
        const double rU = ((minval + cU) - u_i) - 0.0;   // v[j]==0 on U
        if (rU < ub_r || (rU == ub_r && jU < ub_j)) { ub_r = rU; ub_j = jU; ub_i = icur; }
      }

      // --- A-side: update shortest over unscanned assigned columns
      double cr = INFINITY; int cj = 0x7fffffff, cs = -1;
      if (actA) {
        const double r = ((minval + (double)cA) - u_i) - avA;
        if (r < ashA) { ashA = r; apathA = icur; }
        cr = ashA; cj = acolA; cs = lane;
      }
      if (actB) {
        const double r = ((minval + (double)cB) - u_i) - avB;
        if (r < ashB) { ashB = r; apathB = icur; }
        if (ashB < cr || (ashB == cr && acolB < cj)) { cr = ashB; cj = acolB; cs = 64 + lane; }
      }
      #pragma unroll
      for (int off = 32; off; off >>= 1) {
        const double orr = __shfl_xor(cr, off);
        const int    oj  = __shfl_xor(cj, off);
        const int    os  = __shfl_xor(cs, off);
        if (orr < cr || (orr == cr && oj < cj)) { cr = orr; cj = oj; cs = os; }
      }

      // --- decision (uniform)
      if (cr < ub_r || (cr == ub_r && cj < ub_j)) {
        minval = cr;
        if (lane == (cs & 63)) {
          if (cs < 64) { ascA = true; afzA = cr; }
          else         { ascB = true; afzB = cr; }
        }
        const int rA = __shfl(arowA, cs & 63);
        const int rB = __shfl(arowB, cs & 63);
        icur = (cs < 64) ? rA : rB;
      } else {
        minval = ub_r;
        sink = ub_j; sinkpath = ub_i;
      }
    }

    // --- dual updates (owner-side; rows among scanned slots are distinct)
    if (lane == 0) u[cur] += minval;
    if (ascA) { u[arowA] += minval - afzA; avA -= (minval - afzA); }
    if (ascB) { u[arowB] += minval - afzB; avB -= (minval - afzB); }

    // --- augment along the alternating path
    {
      int j = sink, i = sinkpath;
      if (lane == (nA & 63)) {             // append sink as new slot
        if (nA < 64) { acolA = sink; avA = 0.0; arowA = i; }
        else         { acolB = sink; avB = 0.0; arowB = i; }
      }
      if (nA < SLOTC) {                    // fill LDS cost column for the slot
        Clds[lane][nA]      = C[(size_t)lane * NQ + sink];
        Clds[64 + lane][nA] = C[(size_t)(64 + lane) * NQ + sink];
      }
      if (lane == 0) abm[sink >> 6] |= 1ull << (sink & 63);
      nA++;
      for (;;) {
        const int jn = col4row[i];
        if (lane == 0) col4row[i] = (short)j;
        if (i == cur) break;
        j = jn;
        // find slot owning column j via ballot (replaces slot4col table)
        const bool hA = (acolA == j);
        const bool hB = (acolB == j);
        const unsigned long long bal = __ballot(hA || hB);
        const int ln = (int)__builtin_ctzll(bal);
        const int isB = __shfl((int)(hB ? 1 : 0), ln);
        const int pA = __shfl(apathA, ln);
        const int pB = __shfl(apathB, ln);
        const int ni = isB ? pB : pA;
        if (lane == ln) { if (isB) arowB = ni; else arowA = ni; }
        i = ni;
      }
    }
  }

  // output: rows = col4row (query idx), cols = arange(NT), sorted by query idx
  for (int t = lane; t < NT; t += 64) {
    const int q = col4row[t];
    int rank = 0;
    for (int k = 0; k < NT; ++k) rank += (col4row[k] < q);
    outi[rank]      = q;
    outi[NT + rank] = t;
  }
}

extern "C" void kernel_launch(void* const* d_in, const int* in_sizes, int n_in,
                              void* d_out, int out_size, void* d_ws, size_t ws_size,
                              hipStream_t stream) {
  (void)in_sizes; (void)n_in; (void)out_size; (void)ws_size;
  const float* outputs = (const float*)d_in[0];
  const int*   targets = (const int*)d_in[1];
  float* C = (float*)d_ws;                                    // 4 MB
  unsigned long long* S =
      (unsigned long long*)((char*)d_ws + (size_t)NT * NQ * sizeof(float)); // 256 KB
  int* out = (int*)d_out;

  build_cost<<<NQ, 256, 0, stream>>>(outputs, targets, C);
  select_rows<<<NT, 256, 0, stream>>>(C, S);
  lsap_solve<<<1, 64, 0, stream>>>(C, S, out);
}

// Round 5
// 411.183 us; speedup vs baseline: 2.4487x; 1.2265x over previous
//
#include <hip/hip_runtime.h>
#include <hip/hip_bf16.h>
#include <math.h>

#define NQ 8192      // queries (columns of the transposed cost)
#define NC 32000     // classes
#define NT 128       // targets (rows of the transposed cost)
#define SROW 256     // kept (smallest) sorted entries per row
#define SLOTC 128    // assigned-column slots cached in LDS (all of them)

typedef float v4f __attribute__((ext_vector_type(4)));

// ---------------------------------------------------------------------------
// Kernel A: per-row softmax stats + cost build in BOTH orientations.
// C[t][q] (row-major, for select) and Ccol[q][t] (query-major, for the
// solver's coalesced sink-column fill).
// ---------------------------------------------------------------------------
__global__ __launch_bounds__(256) void build_cost(
    const float* __restrict__ outp, const int* __restrict__ tgt,
    float* __restrict__ C, float* __restrict__ Ccol)
{
  const int row = blockIdx.x;
  const int tid = threadIdx.x;
  const float* x = outp + (size_t)row * NC;

  float m = -INFINITY;
  double s = 0.0;
  const v4f* x4 = (const v4f*)x;
  for (int k = tid; k < NC / 4; k += 256) {
    v4f v = __builtin_nontemporal_load(x4 + k);
    float mv = fmaxf(fmaxf(v.x, v.y), fmaxf(v.z, v.w));
    if (mv > m) { s *= exp((double)(m - mv)); m = mv; }
    s += (double)__expf(v.x - m) + (double)__expf(v.y - m)
       + (double)__expf(v.z - m) + (double)__expf(v.w - m);
  }

  __shared__ float  lsm[4];
  __shared__ double lss[4];
  __shared__ float  bM;
  __shared__ double bS;

  float wm = m;
  #pragma unroll
  for (int off = 32; off; off >>= 1) wm = fmaxf(wm, __shfl_xor(wm, off));
  const int wid = tid >> 6;
  if ((tid & 63) == 0) lsm[wid] = wm;
  __syncthreads();
  if (tid == 0) bM = fmaxf(fmaxf(lsm[0], lsm[1]), fmaxf(lsm[2], lsm[3]));
  __syncthreads();
  const float M = bM;

  double s2 = s * exp((double)m - (double)M);
  #pragma unroll
  for (int off = 32; off; off >>= 1) s2 += __shfl_xor(s2, off);
  if ((tid & 63) == 0) lss[wid] = s2;
  __syncthreads();
  if (tid == 0) bS = lss[0] + lss[1] + lss[2] + lss[3];
  __syncthreads();
  const double S = bS;

  if (tid < NT) {
    const int c = tgt[tid];
    const double p = exp((double)x[c] - (double)M) / S;
    const float cv = 1.0f - (float)p;
    C[(size_t)tid * NQ + row]    = cv;
    Ccol[(size_t)row * NT + tid] = cv;
  }
}

// ---------------------------------------------------------------------------
// Kernel B1: per (row, 1024-part) top-256 sorted ascending by (cost_bits, j).
// Keys u64: (f32_bits(c) << 32) | j  (c > 0 so bit order == value order).
// Grid (8, 128). Phase 1: sort each 256-chunk; phase 2: 2 rounds of mirrored
// compare-exchange (keeps 256 smallest, bitonic) + 8-pass bitonic re-merge.
// ---------------------------------------------------------------------------
__global__ __launch_bounds__(256) void select_part(
    const float* __restrict__ C, unsigned long long* __restrict__ S1)
{
  __shared__ unsigned long long key[1024];
  const int part = blockIdx.x, t = blockIdx.y, tid = threadIdx.x;
  const float* crow = C + (size_t)t * NQ + part * 1024;
  for (int i = tid; i < 1024; i += 256)
    key[i] = ((unsigned long long)__float_as_uint(crow[i]) << 32)
           | (unsigned)(part * 1024 + i);

  for (int k = 2; k <= 256; k <<= 1)
    for (int jj = k >> 1; jj > 0; jj >>= 1) {
      __syncthreads();
      for (int w = tid; w < 512; w += 256) {
        const int i1 = ((w & ~(jj - 1)) << 1) | (w & (jj - 1));
        const int i2 = i1 | jj;
        const bool up = (((i1 & 255) & k) == 0);
        const unsigned long long a = key[i1], b = key[i2];
        if ((a > b) == up) { key[i1] = b; key[i2] = a; }
      }
    }

  for (int step = 1; step < 4; step <<= 1) {
    const int npairs = 2 / step;
    __syncthreads();
    for (int w = tid; w < npairs * 256; w += 256) {
      const int p = w >> 8, i = w & 255;
      const int a = ((p * 2 * step) << 8) + i;
      const int b = ((p * 2 * step + step) << 8) + 255 - i;
      const unsigned long long ka = key[a], kb = key[b];
      if (ka > kb) key[a] = kb;
    }
    for (int jj = 128; jj > 0; jj >>= 1) {
      __syncthreads();
      for (int w = tid; w < npairs * 128; w += 256) {
        const int p = w >> 7, q = w & 127;
        const int base = (p * 2 * step) << 8;
        const int i1 = base + (((q & ~(jj - 1)) << 1) | (q & (jj - 1)));
        const int i2 = i1 | jj;
        const unsigned long long a = key[i1], b = key[i2];
        if (a > b) { key[i1] = b; key[i2] = a; }
      }
    }
  }
  __syncthreads();
  S1[((size_t)t * 8 + part) * 256 + tid] = key[tid];
}

// ---------------------------------------------------------------------------
// Kernel B2: merge 8 sorted top-256 lists -> top-256 per row (3 rounds).
// ---------------------------------------------------------------------------
__global__ __launch_bounds__(256) void select_merge(
    const unsigned long long* __restrict__ S1, unsigned long long* __restrict__ S)
{
  __shared__ unsigned long long key[2048];
  const int t = blockIdx.x, tid = threadIdx.x;
  for (int i = tid; i < 2048; i += 256) key[i] = S1[(size_t)t * 2048 + i];

  for (int step = 1; step < 8; step <<= 1) {
    const int npairs = 4 / step;
    __syncthreads();
    for (int w = tid; w < npairs * 256; w += 256) {
      const int p = w >> 8, i = w & 255;
      const int a = ((p * 2 * step) << 8) + i;
      const int b = ((p * 2 * step + step) << 8) + 255 - i;
      const unsigned long long ka = key[a], kb = key[b];
      if (ka > kb) key[a] = kb;
    }
    for (int jj = 128; jj > 0; jj >>= 1) {
      __syncthreads();
      for (int w = tid; w < npairs * 128; w += 256) {
        const int p = w >> 7, q = w & 127;
        const int base = (p * 2 * step) << 8;
        const int i1 = base + (((q & ~(jj - 1)) << 1) | (q & (jj - 1)));
        const int i2 = i1 | jj;
        const unsigned long long a = key[i1], b = key[i2];
        if (a > b) { key[i1] = b; key[i2] = a; }
      }
    }
  }
  __syncthreads();
  S[(size_t)t * SROW + tid] = key[tid];
}

// ---------------------------------------------------------------------------
// DPP lex-min step on (f64 value, i32 idx): bring partner lane's pair via DPP
// (VALU, no LDS) and keep the lex-smaller. Valid for min-reduction with any
// generating xor-mask set; we use xor1, xor2, xor7(row_half_mirror),
// xor15(row_mirror), then shfl_xor 16/32.
// ---------------------------------------------------------------------------
template <int CTRL>
__device__ __forceinline__ void dpp_lexmin(double& cr, int& cj) {
  union { double d; int i[2]; } a, r;
  a.d = cr;
  r.i[0] = __builtin_amdgcn_update_dpp(0, a.i[0], CTRL, 0xF, 0xF, true);
  r.i[1] = __builtin_amdgcn_update_dpp(0, a.i[1], CTRL, 0xF, 0xF, true);
  const int oj = __builtin_amdgcn_update_dpp(0, cj, CTRL, 0xF, 0xF, true);
  const double ov = r.d;
  if (ov < cr || (ov == cr && oj < cj)) { cr = ov; cj = oj; }
}

// ---------------------------------------------------------------------------
// Kernel C: exact JV LSAP, single wave, barrier-free. All A-side costs in
// LDS (Clds, add-swizzled columns so fills are conflict-free); sink-column
// fill is one coalesced 512B read of Ccol issued before the augment walk.
// Semantics identical to the verified R2/R4 solver.
// ---------------------------------------------------------------------------
__global__ __launch_bounds__(64) void lsap_solve(
    const float* __restrict__ Ccol, const unsigned long long* __restrict__ S,
    int* __restrict__ outi)
{
  const int lane = threadIdx.x;

  __shared__ float  Clds[NT][SLOTC];            // 64 KB, [row][(slot+row)&127]
  __shared__ double u[NT];
  __shared__ unsigned long long cand[NT];       // 0 = unset; keys never 0
  __shared__ unsigned long long abm[NQ / 64];   // assigned bitmap
  __shared__ short col4row[NT];
  __shared__ unsigned short cursor[NT];

  int    acolA = -1, acolB = -1;     // column of slot (A: slot=lane, B: 64+lane)
  int    arowA = -1, arowB = -1;     // row4col[col]
  int    apathA = -1, apathB = -1;   // path[col]
  double avA = 0.0, avB = 0.0;       // v[col]
  double ashA = 0.0, ashB = 0.0;     // shortest[col]
  double afzA = 0.0, afzB = 0.0;     // shortest frozen at selection
  bool   ascA = false, ascB = false; // SC[col]
  int    nA = 0;

  u[lane] = 0.0;        u[64 + lane] = 0.0;
  cand[lane] = 0ull;    cand[64 + lane] = 0ull;
  col4row[lane] = -1;   col4row[64 + lane] = -1;
  cursor[lane] = 0;     cursor[64 + lane] = 0;
  abm[lane] = 0ull;     abm[64 + lane] = 0ull;

  for (int cur = 0; cur < NT; ++cur) {
    ashA = INFINITY; ashB = INFINITY; ascA = false; ascB = false;
    double ub_r = INFINITY; int ub_j = 0x7fffffff, ub_i = -1;
    int icur = cur; double minval = 0.0;
    int sink = -1, sinkpath = -1;

    while (sink < 0) {
      const double u_i = u[icur];
      const bool actA = (lane < nA) && !ascA;
      const bool actB = (64 + lane < nA) && !ascB;
      float cA = 0.f, cB = 0.f;
      if (actA) cA = Clds[icur][(lane + icur) & 127];
      if (actB) cB = Clds[icur][(64 + lane + icur) & 127];

      // --- U-side: cached first-unassigned sorted candidate for this row
      unsigned long long kk = cand[icur];
      {
        const int jc = (int)(kk & 0xffffffffu);
        const bool valid = (kk != 0ull) && !((abm[jc >> 6] >> (jc & 63)) & 1ull);
        if (!valid) {
          int pos = cursor[icur];
          for (;;) {
            const unsigned long long k = S[(size_t)icur * SROW + pos + lane];
            const int j = (int)(k & 0xffffffffu);
            const bool asg = (abm[j >> 6] >> (j & 63)) & 1ull;
            const unsigned long long bal = __ballot(!asg);
            if (bal) {
              const int f = __builtin_ctzll(bal);
              kk = __shfl(k, f);
              pos += f;
              break;
            }
            pos += 64;
          }
          if (lane == 0) { cursor[icur] = (unsigned short)pos; cand[icur] = kk; }
        }
      }
      {
        const int    jU = (int)(kk & 0xffffffffu);
        const double cU = (double)__uint_as_float((unsigned)(kk >> 32));
        const double rU = ((minval + cU) - u_i) - 0.0;   // v[j]==0 on U
        if (rU < ub_r || (rU == ub_r && jU < ub_j)) { ub_r = rU; ub_j = jU; ub_i = icur; }
      }

      // --- A-side: update shortest over unscanned assigned columns
      double cr = INFINITY; int cj = 0x7fffffff;
      if (actA) {
        const double r = ((minval + (double)cA) - u_i) - avA;
        if (r < ashA) { ashA = r; apathA = icur; }
        cr = ashA; cj = acolA;
      }
      if (actB) {
        const double r = ((minval + (double)cB) - u_i) - avB;
        if (r < ashB) { ashB = r; apathB = icur; }
        if (ashB < cr || (ashB == cr && acolB < cj)) { cr = ashB; cj = acolB; }
      }
      // VALU lex-min butterfly: DPP xor1, xor2, xor7, xor15, then shfl 16/32
      dpp_lexmin<0xB1>(cr, cj);   // quad_perm(1,0,3,2)  == xor 1
      dpp_lexmin<0x4E>(cr, cj);   // quad_perm(2,3,0,1)  == xor 2
      dpp_lexmin<0x141>(cr, cj);  // row_half_mirror     == xor 7
      dpp_lexmin<0x140>(cr, cj);  // row_mirror          == xor 15
      #pragma unroll
      for (int off = 16; off <= 32; off <<= 1) {
        const double ov = __shfl_xor(cr, off);
        const int    oj = __shfl_xor(cj, off);
        if (ov < cr || (ov == cr && oj < cj)) { cr = ov; cj = oj; }
      }

      // --- decision (uniform)
      if (cr < ub_r || (cr == ub_r && cj < ub_j)) {
        minval = cr;
        // recover owning slot: column cj is owned by exactly one active slot
        const bool mineA = actA && (ashA == cr) && (acolA == cj);
        const bool mineB = actB && (ashB == cr) && (acolB == cj);
        const unsigned long long bal = __ballot(mineA || mineB);
        const int ln  = (int)__builtin_ctzll(bal);
        const int isB = __shfl((int)(mineB ? 1 : 0), ln);
        if (lane == ln) {
          if (isB) { ascB = true; afzB = cr; }
          else     { ascA = true; afzA = cr; }
        }
        const int rA = __shfl(arowA, ln);
        const int rB = __shfl(arowB, ln);
        icur = isB ? rB : rA;
      } else {
        minval = ub_r;
        sink = ub_j; sinkpath = ub_i;
      }
    }

    // --- prefetch sink's cost column (coalesced; hides under duals + walk)
    const int nAold = nA;
    const float fc0 = Ccol[(size_t)sink * NT + lane];
    const float fc1 = Ccol[(size_t)sink * NT + 64 + lane];

    // --- dual updates (owner-side; rows among scanned slots are distinct)
    if (lane == 0) u[cur] += minval;
    if (ascA) { u[arowA] += minval - afzA; avA -= (minval - afzA); }
    if (ascB) { u[arowB] += minval - afzB; avB -= (minval - afzB); }

    // --- augment along the alternating path
    {
      int j = sink, i = sinkpath;
      if (lane == (nAold & 63)) {            // append sink as new slot
        if (nAold < 64) { acolA = sink; avA = 0.0; arowA = i; }
        else            { acolB = sink; avB = 0.0; arowB = i; }
      }
      if (lane == 0) abm[sink >> 6] |= 1ull << (sink & 63);
      nA = nAold + 1;
      for (;;) {
        const int jn = col4row[i];
        if (lane == 0) col4row[i] = (short)j;
        if (i == cur) break;
        j = jn;
        const bool hA = (acolA == j);
        const bool hB = (acolB == j);
        const unsigned long long bal = __ballot(hA || hB);
        const int ln = (int)__builtin_ctzll(bal);
        const int isB = __shfl((int)(hB ? 1 : 0), ln);
        const int pA = __shfl(apathA, ln);
        const int pB = __shfl(apathB, ln);
        const int ni = isB ? pB : pA;
        if (lane == ln) { if (isB) arowB = ni; else arowA = ni; }
        i = ni;
      }
    }

    // --- land the prefetched column into swizzled Clds (conflict-free)
    Clds[lane][(nAold + lane) & 127]           = fc0;
    Clds[64 + lane][(nAold + 64 + lane) & 127] = fc1;
  }

  // output: rows = col4row (query idx), cols = arange(NT), sorted by query idx
  for (int t = lane; t < NT; t += 64) {
    const int q = col4row[t];
    int rank = 0;
    for (int k = 0; k < NT; ++k) rank += (col4row[k] < q);
    outi[rank]      = q;
    outi[NT + rank] = t;
  }
}

extern "C" void kernel_launch(void* const* d_in, const int* in_sizes, int n_in,
                              void* d_out, int out_size, void* d_ws, size_t ws_size,
                              hipStream_t stream) {
  (void)in_sizes; (void)n_in; (void)out_size; (void)ws_size;
  const float* outputs = (const float*)d_in[0];
  const int*   targets = (const int*)d_in[1];
  char* ws = (char*)d_ws;
  float* C    = (float*)ws;                                  // 4 MB
  float* Ccol = (float*)(ws + (size_t)NT * NQ * 4);          // 4 MB
  unsigned long long* S1 =
      (unsigned long long*)(ws + (size_t)NT * NQ * 8);       // 2 MB
  unsigned long long* S =
      (unsigned long long*)(ws + (size_t)NT * NQ * 8 + (size_t)NT * 8 * 256 * 8);
  int* out = (int*)d_out;

  build_cost<<<NQ, 256, 0, stream>>>(outputs, targets, C, Ccol);
  select_part<<<dim3(8, NT), 256, 0, stream>>>(C, S1);
  select_merge<<<NT, 256, 0, stream>>>(S1, S);
  lsap_solve<<<1, 64, 0, stream>>>(Ccol, S, out);
}

// Round 6
// 406.360 us; speedup vs baseline: 2.4778x; 1.0119x over previous
//
#include <hip/hip_runtime.h>
#include <hip/hip_bf16.h>
#include <math.h>

#define NQ 8192      // queries (columns of the transposed cost)
#define NC 32000     // classes
#define NT 128       // targets (rows of the transposed cost)
#define SROW 256     // kept (smallest) sorted entries per row
#define SLOTC 128    // assigned-column slots cached in LDS (all of them)

typedef float v4f __attribute__((ext_vector_type(4)));

// ---------------------------------------------------------------------------
// Kernel A: per-row softmax stats + cost build in BOTH orientations.
// ---------------------------------------------------------------------------
__global__ __launch_bounds__(256) void build_cost(
    const float* __restrict__ outp, const int* __restrict__ tgt,
    float* __restrict__ C, float* __restrict__ Ccol)
{
  const int row = blockIdx.x;
  const int tid = threadIdx.x;
  const float* x = outp + (size_t)row * NC;

  float m = -INFINITY;
  double s = 0.0;
  const v4f* x4 = (const v4f*)x;
  for (int k = tid; k < NC / 4; k += 256) {
    v4f v = __builtin_nontemporal_load(x4 + k);
    float mv = fmaxf(fmaxf(v.x, v.y), fmaxf(v.z, v.w));
    if (mv > m) { s *= exp((double)(m - mv)); m = mv; }
    s += (double)__expf(v.x - m) + (double)__expf(v.y - m)
       + (double)__expf(v.z - m) + (double)__expf(v.w - m);
  }

  __shared__ float  lsm[4];
  __shared__ double lss[4];
  __shared__ float  bM;
  __shared__ double bS;

  float wm = m;
  #pragma unroll
  for (int off = 32; off; off >>= 1) wm = fmaxf(wm, __shfl_xor(wm, off));
  const int wid = tid >> 6;
  if ((tid & 63) == 0) lsm[wid] = wm;
  __syncthreads();
  if (tid == 0) bM = fmaxf(fmaxf(lsm[0], lsm[1]), fmaxf(lsm[2], lsm[3]));
  __syncthreads();
  const float M = bM;

  double s2 = s * exp((double)m - (double)M);
  #pragma unroll
  for (int off = 32; off; off >>= 1) s2 += __shfl_xor(s2, off);
  if ((tid & 63) == 0) lss[wid] = s2;
  __syncthreads();
  if (tid == 0) bS = lss[0] + lss[1] + lss[2] + lss[3];
  __syncthreads();
  const double S = bS;

  if (tid < NT) {
    const int c = tgt[tid];
    const double p = exp((double)x[c] - (double)M) / S;
    const float cv = 1.0f - (float)p;
    C[(size_t)tid * NQ + row]    = cv;
    Ccol[(size_t)row * NT + tid] = cv;
  }
}

// ---------------------------------------------------------------------------
// Kernel B1: per (row, 1024-part) top-256 sorted ascending by (cost_bits, j).
// ---------------------------------------------------------------------------
__global__ __launch_bounds__(256) void select_part(
    const float* __restrict__ C, unsigned long long* __restrict__ S1)
{
  __shared__ unsigned long long key[1024];
  const int part = blockIdx.x, t = blockIdx.y, tid = threadIdx.x;
  const float* crow = C + (size_t)t * NQ + part * 1024;
  for (int i = tid; i < 1024; i += 256)
    key[i] = ((unsigned long long)__float_as_uint(crow[i]) << 32)
           | (unsigned)(part * 1024 + i);

  for (int k = 2; k <= 256; k <<= 1)
    for (int jj = k >> 1; jj > 0; jj >>= 1) {
      __syncthreads();
      for (int w = tid; w < 512; w += 256) {
        const int i1 = ((w & ~(jj - 1)) << 1) | (w & (jj - 1));
        const int i2 = i1 | jj;
        const bool up = (((i1 & 255) & k) == 0);
        const unsigned long long a = key[i1], b = key[i2];
        if ((a > b) == up) { key[i1] = b; key[i2] = a; }
      }
    }

  for (int step = 1; step < 4; step <<= 1) {
    const int npairs = 2 / step;
    __syncthreads();
    for (int w = tid; w < npairs * 256; w += 256) {
      const int p = w >> 8, i = w & 255;
      const int a = ((p * 2 * step) << 8) + i;
      const int b = ((p * 2 * step + step) << 8) + 255 - i;
      const unsigned long long ka = key[a], kb = key[b];
      if (ka > kb) key[a] = kb;
    }
    for (int jj = 128; jj > 0; jj >>= 1) {
      __syncthreads();
      for (int w = tid; w < npairs * 128; w += 256) {
        const int p = w >> 7, q = w & 127;
        const int base = (p * 2 * step) << 8;
        const int i1 = base + (((q & ~(jj - 1)) << 1) | (q & (jj - 1)));
        const int i2 = i1 | jj;
        const unsigned long long a = key[i1], b = key[i2];
        if (a > b) { key[i1] = b; key[i2] = a; }
      }
    }
  }
  __syncthreads();
  S1[((size_t)t * 8 + part) * 256 + tid] = key[tid];
}

// ---------------------------------------------------------------------------
// Kernel B2: merge 8 sorted top-256 lists -> top-256 per row (3 rounds).
// ---------------------------------------------------------------------------
__global__ __launch_bounds__(256) void select_merge(
    const unsigned long long* __restrict__ S1, unsigned long long* __restrict__ S)
{
  __shared__ unsigned long long key[2048];
  const int t = blockIdx.x, tid = threadIdx.x;
  for (int i = tid; i < 2048; i += 256) key[i] = S1[(size_t)t * 2048 + i];

  for (int step = 1; step < 8; step <<= 1) {
    const int npairs = 4 / step;
    __syncthreads();
    for (int w = tid; w < npairs * 256; w += 256) {
      const int p = w >> 8, i = w & 255;
      const int a = ((p * 2 * step) << 8) + i;
      const int b = ((p * 2 * step + step) << 8) + 255 - i;
      const unsigned long long ka = key[a], kb = key[b];
      if (ka > kb) key[a] = kb;
    }
    for (int jj = 128; jj > 0; jj >>= 1) {
      __syncthreads();
      for (int w = tid; w < npairs * 128; w += 256) {
        const int p = w >> 7, q = w & 127;
        const int base = (p * 2 * step) << 8;
        const int i1 = base + (((q & ~(jj - 1)) << 1) | (q & (jj - 1)));
        const int i2 = i1 | jj;
        const unsigned long long a = key[i1], b = key[i2];
        if (a > b) { key[i1] = b; key[i2] = a; }
      }
    }
  }
  __syncthreads();
  S[(size_t)t * SROW + tid] = key[tid];
}

// --------------------------- readlane helpers (uniform idx, VALU-speed) ----
__device__ __forceinline__ int rl_i32(int v, int l) {
  return __builtin_amdgcn_readlane(v, l);
}
__device__ __forceinline__ double rl_f64(double v, int l) {
  union { double d; int i[2]; } a; a.d = v;
  union { int i[2]; double d; } r;
  r.i[0] = __builtin_amdgcn_readlane(a.i[0], l);
  r.i[1] = __builtin_amdgcn_readlane(a.i[1], l);
  return r.d;
}
__device__ __forceinline__ unsigned long long rl_u64(unsigned long long v, int l) {
  union { unsigned long long q; int i[2]; } a; a.q = v;
  union { int i[2]; unsigned long long q; } r;
  r.i[0] = __builtin_amdgcn_readlane(a.i[0], l);
  r.i[1] = __builtin_amdgcn_readlane(a.i[1], l);
  return r.q;
}

// DPP lex-min step on (f64 value, i32 idx).
template <int CTRL>
__device__ __forceinline__ void dpp_lexmin(double& cr, int& cj) {
  union { double d; int i[2]; } a, r;
  a.d = cr;
  r.i[0] = __builtin_amdgcn_update_dpp(0, a.i[0], CTRL, 0xF, 0xF, true);
  r.i[1] = __builtin_amdgcn_update_dpp(0, a.i[1], CTRL, 0xF, 0xF, true);
  const int oj = __builtin_amdgcn_update_dpp(0, cj, CTRL, 0xF, 0xF, true);
  const double ov = r.d;
  if (ov < cr || (ov == cr && oj < cj)) { cr = ov; cj = oj; }
}

// ---------------------------------------------------------------------------
// Kernel C: exact JV LSAP, single wave, barrier-free.
// vs R5: all wave-uniform-index shuffles -> v_readlane; cand/cursor live in
// registers (2 rows per lane) with eager sink-invalidation, removing the
// dependent cand->bitmap LDS chain from the steady-state iteration.
// Semantics identical to the verified R2/R4/R5 solver.
// ---------------------------------------------------------------------------
__global__ __launch_bounds__(64) void lsap_solve(
    const float* __restrict__ Ccol, const unsigned long long* __restrict__ S,
    int* __restrict__ outi)
{
  const int lane = threadIdx.x;

  __shared__ float  Clds[NT][SLOTC];            // 64 KB, [row][(slot+row)&127]
  __shared__ double u[NT];
  __shared__ unsigned long long abm[NQ / 64];   // assigned bitmap (probe-only)
  __shared__ short col4row[NT];

  int    acolA = -1, acolB = -1;     // column of slot (A: slot=lane, B: 64+lane)
  int    arowA = -1, arowB = -1;     // row4col[col]
  int    apathA = -1, apathB = -1;   // path[col]
  double avA = 0.0, avB = 0.0;       // v[col]
  double ashA = 0.0, ashB = 0.0;     // shortest[col]
  double afzA = 0.0, afzB = 0.0;     // shortest frozen at selection
  bool   ascA = false, ascB = false; // SC[col]
  int    nA = 0;

  // per-row U-candidate cache in registers: lane L owns rows L and 64+L.
  // 0 = unset/invalid; keys are never 0 for this data (c>0 or j!=0).
  unsigned long long candA = 0ull, candB = 0ull;
  int curA = 0, curB = 0;            // sorted-row cursors

  u[lane] = 0.0;        u[64 + lane] = 0.0;
  col4row[lane] = -1;   col4row[64 + lane] = -1;
  abm[lane] = 0ull;     abm[64 + lane] = 0ull;

  for (int cur = 0; cur < NT; ++cur) {
    ashA = INFINITY; ashB = INFINITY; ascA = false; ascB = false;
    double ub_r = INFINITY; int ub_j = 0x7fffffff, ub_i = -1;
    int icur = cur; double minval = 0.0;
    int sink = -1, sinkpath = -1;

    while (sink < 0) {
      const double u_i = u[icur];
      const bool actA = (lane < nA) && !ascA;
      const bool actB = (64 + lane < nA) && !ascB;
      float cA = 0.f, cB = 0.f;
      if (actA) cA = Clds[icur][(lane + icur) & 127];
      if (actB) cB = Clds[icur][(64 + lane + icur) & 127];

      // --- U-side: register-cached first-unassigned sorted candidate
      unsigned long long kk = (icur < 64) ? rl_u64(candA, icur)
                                          : rl_u64(candB, icur - 64);
      if (kk == 0ull) {   // probe the sorted row (rare)
        int pos = (icur < 64) ? rl_i32(curA, icur) : rl_i32(curB, icur - 64);
        for (;;) {
          const unsigned long long k = S[(size_t)icur * SROW + pos + lane];
          const int j = (int)(k & 0xffffffffu);
          const bool asg = (abm[j >> 6] >> (j & 63)) & 1ull;
          const unsigned long long bal = __ballot(!asg);
          if (bal) {
            const int f = __builtin_ctzll(bal);
            kk = rl_u64(k, f);
            pos += f;
            break;
          }
          pos += 64;
        }
        if (lane == (icur & 63)) {
          if (icur < 64) { candA = kk; curA = pos; }
          else           { candB = kk; curB = pos; }
        }
      }
      {
        const int    jU = (int)(kk & 0xffffffffu);
        const double cU = (double)__uint_as_float((unsigned)(kk >> 32));
        const double rU = ((minval + cU) - u_i) - 0.0;   // v[j]==0 on U
        if (rU < ub_r || (rU == ub_r && jU < ub_j)) { ub_r = rU; ub_j = jU; ub_i = icur; }
      }

      // --- A-side: update shortest over unscanned assigned columns
      double cr = INFINITY; int cj = 0x7fffffff;
      if (actA) {
        const double r = ((minval + (double)cA) - u_i) - avA;
        if (r < ashA) { ashA = r; apathA = icur; }
        cr = ashA; cj = acolA;
      }
      if (actB) {
        const double r = ((minval + (double)cB) - u_i) - avB;
        if (r < ashB) { ashB = r; apathB = icur; }
        if (ashB < cr || (ashB == cr && acolB < cj)) { cr = ashB; cj = acolB; }
      }
      // lex-min: DPP within 16-lane groups, then readlane across groups
      dpp_lexmin<0xB1>(cr, cj);   // quad_perm(1,0,3,2)  == xor 1
      dpp_lexmin<0x4E>(cr, cj);   // quad_perm(2,3,0,1)  == xor 2
      dpp_lexmin<0x141>(cr, cj);  // row_half_mirror     == xor 7
      dpp_lexmin<0x140>(cr, cj);  // row_mirror          == xor 15
      {
        double bv = rl_f64(cr, 0);  int bj = rl_i32(cj, 0);
        const double g1 = rl_f64(cr, 16); const int j1 = rl_i32(cj, 16);
        if (g1 < bv || (g1 == bv && j1 < bj)) { bv = g1; bj = j1; }
        const double g2 = rl_f64(cr, 32); const int j2 = rl_i32(cj, 32);
        if (g2 < bv || (g2 == bv && j2 < bj)) { bv = g2; bj = j2; }
        const double g3 = rl_f64(cr, 48); const int j3 = rl_i32(cj, 48);
        if (g3 < bv || (g3 == bv && j3 < bj)) { bv = g3; bj = j3; }
        cr = bv; cj = bj;
      }

      // --- decision (uniform)
      if (cr < ub_r || (cr == ub_r && cj < ub_j)) {
        minval = cr;
        const bool mineA = actA && (ashA == cr) && (acolA == cj);
        const bool mineB = actB && (ashB == cr) && (acolB == cj);
        const unsigned long long bal = __ballot(mineA || mineB);
        const int ln  = (int)__builtin_ctzll(bal);
        const int isB = rl_i32(mineB ? 1 : 0, ln);
        if (lane == ln) {
          if (isB) { ascB = true; afzB = cr; }
          else     { ascA = true; afzA = cr; }
        }
        icur = isB ? rl_i32(arowB, ln) : rl_i32(arowA, ln);
      } else {
        minval = ub_r;
        sink = ub_j; sinkpath = ub_i;
      }
    }

    // --- prefetch sink's cost column (coalesced; hides under duals + walk)
    const int nAold = nA;
    const float fc0 = Ccol[(size_t)sink * NT + lane];
    const float fc1 = Ccol[(size_t)sink * NT + 64 + lane];

    // --- dual updates (owner-side; rows among scanned slots are distinct)
    if (lane == 0) u[cur] += minval;
    if (ascA) { u[arowA] += minval - afzA; avA -= (minval - afzA); }
    if (ascB) { u[arowB] += minval - afzB; avB -= (minval - afzB); }

    // --- augment along the alternating path
    {
      int j = sink, i = sinkpath;
      if (lane == (nAold & 63)) {            // append sink as new slot
        if (nAold < 64) { acolA = sink; avA = 0.0; arowA = i; }
        else            { acolB = sink; avB = 0.0; arowB = i; }
      }
      if (lane == 0) abm[sink >> 6] |= 1ull << (sink & 63);
      nA = nAold + 1;
      for (;;) {
        const int jn = col4row[i];
        if (lane == 0) col4row[i] = (short)j;
        if (i == cur) break;
        j = jn;
        const bool hA = (acolA == j);
        const bool hB = (acolB == j);
        const unsigned long long bal = __ballot(hA || hB);
        const int ln = (int)__builtin_ctzll(bal);
        const int isB = rl_i32(hB ? 1 : 0, ln);
        const int ni = isB ? rl_i32(apathB, ln) : rl_i32(apathA, ln);
        if (lane == ln) { if (isB) arowB = ni; else arowA = ni; }
        i = ni;
      }
    }

    // --- eager invalidation of register cand cache (sink newly assigned)
    if ((int)(candA & 0xffffffffu) == sink) candA = 0ull;
    if ((int)(candB & 0xffffffffu) == sink) candB = 0ull;

    // --- land the prefetched column into swizzled Clds (conflict-free)
    Clds[lane][(nAold + lane) & 127]           = fc0;
    Clds[64 + lane][(nAold + 64 + lane) & 127] = fc1;
  }

  // output: rows = col4row (query idx), cols = arange(NT), sorted by query idx
  for (int t = lane; t < NT; t += 64) {
    const int q = col4row[t];
    int rank = 0;
    for (int k = 0; k < NT; ++k) rank += (col4row[k] < q);
    outi[rank]      = q;
    outi[NT + rank] = t;
  }
}

extern "C" void kernel_launch(void* const* d_in, const int* in_sizes, int n_in,
                              void* d_out, int out_size, void* d_ws, size_t ws_size,
                              hipStream_t stream) {
  (void)in_sizes; (void)n_in; (void)out_size; (void)ws_size;
  const float* outputs = (const float*)d_in[0];
  const int*   targets = (const int*)d_in[1];
  char* ws = (char*)d_ws;
  float* C    = (float*)ws;                                  // 4 MB
  float* Ccol = (float*)(ws + (size_t)NT * NQ * 4);          // 4 MB
  unsigned long long* S1 =
      (unsigned long long*)(ws + (size_t)NT * NQ * 8);       // 2 MB
  unsigned long long* S =
      (unsigned long long*)(ws + (size_t)NT * NQ * 8 + (size_t)NT * 8 * 256 * 8);
  int* out = (int*)d_out;

  build_cost<<<NQ, 256, 0, stream>>>(outputs, targets, C, Ccol);
  select_part<<<dim3(8, NT), 256, 0, stream>>>(C, S1);
  select_merge<<<NT, 256, 0, stream>>>(S1, S);
  lsap_solve<<<1, 64, 0, stream>>>(Ccol, S, out);
}

// Round 7
// 337.902 us; speedup vs baseline: 2.9798x; 1.2026x over previous
//
#include <hip/hip_runtime.h>
#include <hip/hip_bf16.h>
#include <math.h>

#define NQ 8192      // queries (columns of the transposed cost)
#define NC 32000     // classes
#define NT 128       // targets (rows of the transposed cost)
#define SROW 256     // kept (smallest) sorted entries per row
#define SLOTC 128    // assigned-column slots cached in LDS (all of them)

typedef float v4f __attribute__((ext_vector_type(4)));

// ---------------------------------------------------------------------------
// Kernel A: per-row softmax stats + cost build in BOTH orientations.
// ---------------------------------------------------------------------------
__global__ __launch_bounds__(256) void build_cost(
    const float* __restrict__ outp, const int* __restrict__ tgt,
    float* __restrict__ C, float* __restrict__ Ccol)
{
  const int row = blockIdx.x;
  const int tid = threadIdx.x;
  const float* x = outp + (size_t)row * NC;

  float m = -INFINITY;
  double s = 0.0;
  const v4f* x4 = (const v4f*)x;
  for (int k = tid; k < NC / 4; k += 256) {
    v4f v = __builtin_nontemporal_load(x4 + k);
    float mv = fmaxf(fmaxf(v.x, v.y), fmaxf(v.z, v.w));
    if (mv > m) { s *= exp((double)(m - mv)); m = mv; }
    s += (double)__expf(v.x - m) + (double)__expf(v.y - m)
       + (double)__expf(v.z - m) + (double)__expf(v.w - m);
  }

  __shared__ float  lsm[4];
  __shared__ double lss[4];
  __shared__ float  bM;
  __shared__ double bS;

  float wm = m;
  #pragma unroll
  for (int off = 32; off; off >>= 1) wm = fmaxf(wm, __shfl_xor(wm, off));
  const int wid = tid >> 6;
  if ((tid & 63) == 0) lsm[wid] = wm;
  __syncthreads();
  if (tid == 0) bM = fmaxf(fmaxf(lsm[0], lsm[1]), fmaxf(lsm[2], lsm[3]));
  __syncthreads();
  const float M = bM;

  double s2 = s * exp((double)m - (double)M);
  #pragma unroll
  for (int off = 32; off; off >>= 1) s2 += __shfl_xor(s2, off);
  if ((tid & 63) == 0) lss[wid] = s2;
  __syncthreads();
  if (tid == 0) bS = lss[0] + lss[1] + lss[2] + lss[3];
  __syncthreads();
  const double S = bS;

  if (tid < NT) {
    const int c = tgt[tid];
    const double p = exp((double)x[c] - (double)M) / S;
    const float cv = 1.0f - (float)p;
    C[(size_t)tid * NQ + row]    = cv;
    Ccol[(size_t)row * NT + tid] = cv;
  }
}

// ---------------------------------------------------------------------------
// Kernel B1: per (row, 1024-part) top-256 sorted ascending by (cost_bits, j).
// ---------------------------------------------------------------------------
__global__ __launch_bounds__(256) void select_part(
    const float* __restrict__ C, unsigned long long* __restrict__ S1)
{
  __shared__ unsigned long long key[1024];
  const int part = blockIdx.x, t = blockIdx.y, tid = threadIdx.x;
  const float* crow = C + (size_t)t * NQ + part * 1024;
  for (int i = tid; i < 1024; i += 256)
    key[i] = ((unsigned long long)__float_as_uint(crow[i]) << 32)
           | (unsigned)(part * 1024 + i);

  for (int k = 2; k <= 256; k <<= 1)
    for (int jj = k >> 1; jj > 0; jj >>= 1) {
      __syncthreads();
      for (int w = tid; w < 512; w += 256) {
        const int i1 = ((w & ~(jj - 1)) << 1) | (w & (jj - 1));
        const int i2 = i1 | jj;
        const bool up = (((i1 & 255) & k) == 0);
        const unsigned long long a = key[i1], b = key[i2];
        if ((a > b) == up) { key[i1] = b; key[i2] = a; }
      }
    }

  for (int step = 1; step < 4; step <<= 1) {
    const int npairs = 2 / step;
    __syncthreads();
    for (int w = tid; w < npairs * 256; w += 256) {
      const int p = w >> 8, i = w & 255;
      const int a = ((p * 2 * step) << 8) + i;
      const int b = ((p * 2 * step + step) << 8) + 255 - i;
      const unsigned long long ka = key[a], kb = key[b];
      if (ka > kb) key[a] = kb;
    }
    for (int jj = 128; jj > 0; jj >>= 1) {
      __syncthreads();
      for (int w = tid; w < npairs * 128; w += 256) {
        const int p = w >> 7, q = w & 127;
        const int base = (p * 2 * step) << 8;
        const int i1 = base + (((q & ~(jj - 1)) << 1) | (q & (jj - 1)));
        const int i2 = i1 | jj;
        const unsigned long long a = key[i1], b = key[i2];
        if (a > b) { key[i1] = b; key[i2] = a; }
      }
    }
  }
  __syncthreads();
  S1[((size_t)t * 8 + part) * 256 + tid] = key[tid];
}

// ---------------------------------------------------------------------------
// Kernel B2: merge 8 sorted top-256 lists -> top-256 per row (3 rounds).
// ---------------------------------------------------------------------------
__global__ __launch_bounds__(256) void select_merge(
    const unsigned long long* __restrict__ S1, unsigned long long* __restrict__ S)
{
  __shared__ unsigned long long key[2048];
  const int t = blockIdx.x, tid = threadIdx.x;
  for (int i = tid; i < 2048; i += 256) key[i] = S1[(size_t)t * 2048 + i];

  for (int step = 1; step < 8; step <<= 1) {
    const int npairs = 4 / step;
    __syncthreads();
    for (int w = tid; w < npairs * 256; w += 256) {
      const int p = w >> 8, i = w & 255;
      const int a = ((p * 2 * step) << 8) + i;
      const int b = ((p * 2 * step + step) << 8) + 255 - i;
      const unsigned long long ka = key[a], kb = key[b];
      if (ka > kb) key[a] = kb;
    }
    for (int jj = 128; jj > 0; jj >>= 1) {
      __syncthreads();
      for (int w = tid; w < npairs * 128; w += 256) {
        const int p = w >> 7, q = w & 127;
        const int base = (p * 2 * step) << 8;
        const int i1 = base + (((q & ~(jj - 1)) << 1) | (q & (jj - 1)));
        const int i2 = i1 | jj;
        const unsigned long long a = key[i1], b = key[i2];
        if (a > b) { key[i1] = b; key[i2] = a; }
      }
    }
  }
  __syncthreads();
  S[(size_t)t * SROW + tid] = key[tid];
}

// --------------------------- readlane helpers ------------------------------
__device__ __forceinline__ int rl_i32(int v, int l) {
  return __builtin_amdgcn_readlane(v, l);
}
__device__ __forceinline__ double rl_f64(double v, int l) {
  union { double d; int i[2]; } a; a.d = v;
  union { int i[2]; double d; } r;
  r.i[0] = __builtin_amdgcn_readlane(a.i[0], l);
  r.i[1] = __builtin_amdgcn_readlane(a.i[1], l);
  return r.d;
}
__device__ __forceinline__ unsigned long long rl_u64(unsigned long long v, int l) {
  union { unsigned long long q; int i[2]; } a; a.q = v;
  union { int i[2]; unsigned long long q; } r;
  r.i[0] = __builtin_amdgcn_readlane(a.i[0], l);
  r.i[1] = __builtin_amdgcn_readlane(a.i[1], l);
  return r.q;
}

// DPP value-only f64 min step (no NaNs in this kernel; zeros sign-safe).
template <int CTRL>
__device__ __forceinline__ double dpp_min_f64(double cr) {
  union { double d; int i[2]; } a, r;
  a.d = cr;
  r.i[0] = __builtin_amdgcn_update_dpp(0, a.i[0], CTRL, 0xF, 0xF, true);
  r.i[1] = __builtin_amdgcn_update_dpp(0, a.i[1], CTRL, 0xF, 0xF, true);
  return fmin(cr, r.d);
}

// ---------------------------------------------------------------------------
// Kernel C: exact JV LSAP, single wave, barrier-free.
// vs R6: value-only v_min_f64 reduce (winner slot recovered via ballot;
// column tie-break exact via rare multi-match path); u & col4row registered
// (dual deltas routed through LDS du[]); cand pre-seeded with S[row][0].
// Decision semantics identical to the verified R2..R6 solver.
// ---------------------------------------------------------------------------
__global__ __launch_bounds__(64) void lsap_solve(
    const float* __restrict__ Ccol, const unsigned long long* __restrict__ S,
    int* __restrict__ outi)
{
  const int lane = threadIdx.x;

  __shared__ float  Clds[NT][SLOTC];            // 64 KB, [row][(slot+row)&127]
  __shared__ double du[NT];                     // dual-delta routing
  __shared__ unsigned long long abm[NQ / 64];   // assigned bitmap (probe-only)
  __shared__ short col4row_s[NT];               // staging for the final sort

  int    acolA = -1, acolB = -1;     // column of slot (A: slot=lane, B: 64+lane)
  int    arowA = -1, arowB = -1;     // row4col[col]
  int    apathA = -1, apathB = -1;   // path[col]
  double avA = 0.0, avB = 0.0;       // v[col]
  double ashA = 0.0, ashB = 0.0;     // shortest[col]
  double afzA = 0.0, afzB = 0.0;     // shortest frozen at selection
  bool   ascA = false, ascB = false; // SC[col]
  int    nA = 0;

  // lane L owns rows L and 64+L:
  double uA = 0.0, uB = 0.0;                       // u[row]
  int    c4rA = -1, c4rB = -1;                     // col4row[row]
  unsigned long long candA, candB;                 // cached first-unassigned key
  int    curA = 0, curB = 0;                       // sorted-row cursors

  abm[lane] = 0ull;  abm[64 + lane] = 0ull;
  // pre-seed cand with each row's global-min key (valid: nothing assigned yet)
  candA = S[(size_t)lane * SROW];
  candB = S[(size_t)(64 + lane) * SROW];

  for (int cur = 0; cur < NT; ++cur) {
    ashA = INFINITY; ashB = INFINITY; ascA = false; ascB = false;
    double ub_r = INFINITY; int ub_j = 0x7fffffff, ub_i = -1;
    int icur = cur; double minval = 0.0;
    int sink = -1, sinkpath = -1;

    while (sink < 0) {
      const double u_i = (icur < 64) ? rl_f64(uA, icur) : rl_f64(uB, icur - 64);
      const bool actA = (lane < nA) && !ascA;
      const bool actB = (64 + lane < nA) && !ascB;
      float cA = 0.f, cB = 0.f;
      if (actA) cA = Clds[icur][(lane + icur) & 127];
      if (actB) cB = Clds[icur][(64 + lane + icur) & 127];

      // --- U-side: register-cached first-unassigned sorted candidate
      unsigned long long kk = (icur < 64) ? rl_u64(candA, icur)
                                          : rl_u64(candB, icur - 64);
      if (kk == 0ull) {   // probe the sorted row (rare)
        int pos = (icur < 64) ? rl_i32(curA, icur) : rl_i32(curB, icur - 64);
        for (;;) {
          const unsigned long long k = S[(size_t)icur * SROW + pos + lane];
          const int j = (int)(k & 0xffffffffu);
          const bool asg = (abm[j >> 6] >> (j & 63)) & 1ull;
          const unsigned long long bal = __ballot(!asg);
          if (bal) {
            const int f = __builtin_ctzll(bal);
            kk = rl_u64(k, f);
            pos += f;
            break;
          }
          pos += 64;
        }
        if (lane == (icur & 63)) {
          if (icur < 64) { candA = kk; curA = pos; }
          else           { candB = kk; curB = pos; }
        }
      }
      {
        const int    jU = (int)(kk & 0xffffffffu);
        const double cU = (double)__uint_as_float((unsigned)(kk >> 32));
        const double rU = ((minval + cU) - u_i) - 0.0;   // v[j]==0 on U
        if (rU < ub_r || (rU == ub_r && jU < ub_j)) { ub_r = rU; ub_j = jU; ub_i = icur; }
      }

      // --- A-side: update shortest over unscanned assigned columns
      if (actA) {
        const double r = ((minval + (double)cA) - u_i) - avA;
        if (r < ashA) { ashA = r; apathA = icur; }
      }
      if (actB) {
        const double r = ((minval + (double)cB) - u_i) - avB;
        if (r < ashB) { ashB = r; apathB = icur; }
      }
      // value-only min: per-lane pair, DPP within 16-groups, readlane across
      double cr = actA ? ashA : INFINITY;
      if (actB) cr = fmin(cr, ashB);
      cr = dpp_min_f64<0xB1>(cr);    // quad_perm(1,0,3,2)  == xor 1
      cr = dpp_min_f64<0x4E>(cr);    // quad_perm(2,3,0,1)  == xor 2
      cr = dpp_min_f64<0x141>(cr);   // row_half_mirror     == xor 7
      cr = dpp_min_f64<0x140>(cr);   // row_mirror          == xor 15
      cr = fmin(fmin(rl_f64(cr, 0), rl_f64(cr, 16)),
                fmin(rl_f64(cr, 32), rl_f64(cr, 48)));

      // --- recover winning slot (unique match fast path; exact ties rare)
      const bool mA = actA && (ashA == cr);
      const bool mB = actB && (ashB == cr);
      const unsigned long long balA = __ballot(mA);
      const unsigned long long balB = __ballot(mB);
      int ln = -1, isB = 0, cj = 0x7fffffff;
      if (__popcll(balA) + __popcll(balB) == 1) {
        isB = (balA == 0ull);
        ln  = (int)__builtin_ctzll(balA | balB);
        cj  = isB ? rl_i32(acolB, ln) : rl_i32(acolA, ln);
      } else if ((balA | balB) != 0ull) {
        unsigned long long ba = balA;
        while (ba) {
          const int l = (int)__builtin_ctzll(ba); ba &= ba - 1;
          const int c = rl_i32(acolA, l);
          if (c < cj) { cj = c; ln = l; isB = 0; }
        }
        unsigned long long bb = balB;
        while (bb) {
          const int l = (int)__builtin_ctzll(bb); bb &= bb - 1;
          const int c = rl_i32(acolB, l);
          if (c < cj) { cj = c; ln = l; isB = 1; }
        }
      }

      // --- decision (uniform)
      if (cr < ub_r || (cr == ub_r && cj < ub_j)) {
        minval = cr;
        if (lane == ln) {
          if (isB) { ascB = true; afzB = cr; }
          else     { ascA = true; afzA = cr; }
        }
        icur = isB ? rl_i32(arowB, ln) : rl_i32(arowA, ln);
      } else {
        minval = ub_r;
        sink = ub_j; sinkpath = ub_i;
      }
    }

    // --- prefetch sink's cost column (coalesced; hides under duals + walk)
    const int nAold = nA;
    const float fc0 = Ccol[(size_t)sink * NT + lane];
    const float fc1 = Ccol[(size_t)sink * NT + 64 + lane];

    // --- dual updates: route owner-side deltas to row-owner registers
    du[lane] = 0.0; du[64 + lane] = 0.0;
    if (ascA) { du[arowA] = minval - afzA; avA -= (minval - afzA); }
    if (ascB) { du[arowB] = minval - afzB; avB -= (minval - afzB); }
    uA += du[lane];
    uB += du[64 + lane];
    if (lane == (cur & 63)) { if (cur < 64) uA += minval; else uB += minval; }

    // --- augment along the alternating path
    {
      int j = sink, i = sinkpath;
      if (lane == (nAold & 63)) {            // append sink as new slot
        if (nAold < 64) { acolA = sink; avA = 0.0; arowA = i; }
        else            { acolB = sink; avB = 0.0; arowB = i; }
      }
      if (lane == 0) abm[sink >> 6] |= 1ull << (sink & 63);
      nA = nAold + 1;
      for (;;) {
        const int jn = (i < 64) ? rl_i32(c4rA, i) : rl_i32(c4rB, i - 64);
        if (lane == (i & 63)) { if (i < 64) c4rA = j; else c4rB = j; }
        if (i == cur) break;
        j = jn;
        const bool hA = (acolA == j);
        const bool hB = (acolB == j);
        const unsigned long long bal = __ballot(hA || hB);
        const int ln2 = (int)__builtin_ctzll(bal);
        const int isB2 = rl_i32(hB ? 1 : 0, ln2);
        const int ni = isB2 ? rl_i32(apathB, ln2) : rl_i32(apathA, ln2);
        if (lane == ln2) { if (isB2) arowB = ni; else arowA = ni; }
        i = ni;
      }
    }

    // --- eager invalidation of register cand cache (sink newly assigned)
    if ((int)(candA & 0xffffffffu) == sink) candA = 0ull;
    if ((int)(candB & 0xffffffffu) == sink) candB = 0ull;

    // --- land the prefetched column into swizzled Clds (conflict-free)
    Clds[lane][(nAold + lane) & 127]           = fc0;
    Clds[64 + lane][(nAold + 64 + lane) & 127] = fc1;
  }

  // output: rows = col4row (query idx), cols = arange(NT), sorted by query idx
  col4row_s[lane]      = (short)c4rA;
  col4row_s[64 + lane] = (short)c4rB;
  for (int t = lane; t < NT; t += 64) {
    const int q = col4row_s[t];
    int rank = 0;
    for (int k = 0; k < NT; ++k) rank += (col4row_s[k] < q);
    outi[rank]      = q;
    outi[NT + rank] = t;
  }
}

extern "C" void kernel_launch(void* const* d_in, const int* in_sizes, int n_in,
                              void* d_out, int out_size, void* d_ws, size_t ws_size,
                              hipStream_t stream) {
  (void)in_sizes; (void)n_in; (void)out_size; (void)ws_size;
  const float* outputs = (const float*)d_in[0];
  const int*   targets = (const int*)d_in[1];
  char* ws = (char*)d_ws;
  float* C    = (float*)ws;                                  // 4 MB
  float* Ccol = (float*)(ws + (size_t)NT * NQ * 4);          // 4 MB
  unsigned long long* S1 =
      (unsigned long long*)(ws + (size_t)NT * NQ * 8);       // 2 MB
  unsigned long long* S =
      (unsigned long long*)(ws + (size_t)NT * NQ * 8 + (size_t)NT * 8 * 256 * 8);
  int* out = (int*)d_out;

  build_cost<<<NQ, 256, 0, stream>>>(outputs, targets, C, Ccol);
  select_part<<<dim3(8, NT), 256, 0, stream>>>(C, S1);
  select_merge<<<NT, 256, 0, stream>>>(S1, S);
  lsap_solve<<<1, 64, 0, stream>>>(Ccol, S, out);
}